// Round 1
// baseline (184.184 us; speedup 1.0000x reference)
//
#include <hip/hip_runtime.h>

typedef unsigned int u32;
typedef unsigned long long u64;
typedef float v2f __attribute__((ext_vector_type(2)));
typedef float v4f __attribute__((ext_vector_type(4)));

#define NBATCH 8
#define NPTS   4096
#define NQTOT  (NBATCH * NPTS)   /* 32768 */
#define KNN    16
#define NBASIS 8
#define OUTM   64
#define NSPLIT 8
#define WIN    (NPTS / NSPLIT)   /* 512 candidates per window */
#define QPB    64
#define TKNN   (QPB * NSPLIT)    /* 512 threads = 8 waves */
#define GRP    8
#define BUFCAP 64
/* per-query LDS row: 64 funnel slots + 16 t16 slots + 1 pad (odd stride) */
#define ROWSTR 81
#define TOFF   64
/* prune margin in d^2 space: fp32 error of (2s+|q|^2) vs exact d2 is <1e-4
 * at these magnitudes; 2e-3 gives >20x headroom. False admits are discarded
 * by the exact-key merge, so kNN selection stays bit-identical. */
#define PMARGIN 2e-3f

// sentinel: d2 = +inf, idx = all-ones (sorts last)
#define SENT 0x7f800000ffffffffull

__device__ __forceinline__ void ce(u64& x, u64& y) {
  u64 a = x, b = y;
  bool sw = b < a;
  x = sw ? b : a;
  y = sw ? a : b;
}

// Batcher odd-even mergesort network (fully unrolled).
template <int N>
__device__ __forceinline__ void oems_sort(u64* a) {
#pragma unroll
  for (int p = 1; p < N; p <<= 1) {
#pragma unroll
    for (int k = p; k >= 1; k >>= 1) {
#pragma unroll
      for (int j = k & (p - 1); j + k < N; j += 2 * k) {
#pragma unroll
        for (int i = 0; i < k; ++i) {
          int lo = i + j, hi = i + j + k;
          if (hi < N && (lo / (2 * p)) == (hi / (2 * p)))
            ce(a[lo], a[hi]);
        }
      }
    }
  }
}

// t, a sorted asc -> t = smallest 16 of union, sorted asc.
__device__ __forceinline__ void merge16(u64 t[16], const u64 a[16]) {
  u64 m[16];
#pragma unroll
  for (int i = 0; i < 16; ++i) {
    u64 x = t[i], y = a[15 - i];
    m[i] = (x < y) ? x : y;
  }
#pragma unroll
  for (int k = 8; k >= 1; k >>= 1) {
#pragma unroll
    for (int i = 0; i < 16; ++i) {
      if ((i & k) == 0) ce(m[i], m[i | k]);
    }
  }
#pragma unroll
  for (int i = 0; i < 16; ++i) t[i] = m[i];
}

// Bit-exact d2 for a candidate pair: ((dx^2+dy^2)+dz^2), no FMA contraction.
// float2 ext-vector ops lower to v_pk_{add,mul}_f32 (IEEE-identical rounding;
// verified bit-exact vs reference rounds 5-8).
__device__ __forceinline__ v2f d2pair(v2f cx, v2f cy, v2f cz, v2f qx, v2f qy,
                                      v2f qz) {
#pragma clang fp contract(off)
  v2f dx = cx - qx;
  v2f dy = cy - qy;
  v2f dz = cz - qz;
  v2f d2 = (dx * dx + dy * dy) + dz * dz;
  return d2;
}

// Scalar bit-exact d2, identical rounding to d2pair / the JAX reference.
__device__ __forceinline__ float d2s(float cx, float cy, float cz, float qx,
                                     float qy, float qz) {
#pragma clang fp contract(off)
  float dx = cx - qx;
  float dy = cy - qy;
  float dz = cz - qz;
  return (dx * dx + dy * dy) + dz * dz;
}

// Fused kNN + tensor-product features, de-serialized funnel version.
// Block = 64 queries x 8 disjoint windows. Running top-16 per query lives in
// the query's LDS row (sT); phase digests rotate across waves; epilogue-M is
// distributed over waves 0-3 (one (query,quarter) per thread) with LDS
// reduction. Main scan prunes in half-norm/dot space (3 packed FMA per 2
// candidates) with a conservative margin; exact bit-ordered d2 is computed
// only for survivors. NO __launch_bounds__ min-waves: rounds 7/8 measured
// forced VGPR (40/64) -> scratch spills (+48/+11 MB HBM).
__global__ __launch_bounds__(TKNN) void se3_kernel(
    const float* __restrict__ Xp, const float* __restrict__ Yp,
    const float* __restrict__ Zp, const float* __restrict__ Hp,
    const float* __restrict__ Wmat, float* __restrict__ out) {
  __shared__ u64 sBuf[QPB * ROWSTR];  // 41.5 KB: funnel + t16 per query row
  __shared__ u32 sCnt[QPB];
  __shared__ float sThr[QPB];
  __shared__ float sM[QPB * 25];      // reduced M[8][3], stride 25

  const int b = blockIdx.x;
  const int qg = blockIdx.y;
  const int tid = threadIdx.x;
  const int ql = tid & 63;
  const int sp = tid >> 6;  // window id, wave-uniform
  const int qi = qg * QPB + ql;
  const int base = b * NPTS;

  if (tid < QPB) sCnt[tid] = 0;

  // per-lane query coords (coalesced)
  const float qx = Xp[base + qi];
  const float qy = Yp[base + qi];
  const float qz = Zp[base + qi];
  const v2f qxx = {qx, qx}, qyy = {qy, qy}, qzz = {qz, qz};
  const v4f qx4 = {qx, qx, qx, qx};
  const v4f qy4 = {qy, qy, qy, qy};
  const v4f qz4 = {qz, qz, qz, qz};

  // wave-uniform candidate window -> uniform loads feeding vector math
  const int wbase = __builtin_amdgcn_readfirstlane(sp * WIN);
  const v2f* xs2 = (const v2f*)(Xp + base + wbase);
  const v2f* ys2 = (const v2f*)(Yp + base + wbase);
  const v2f* zs2 = (const v2f*)(Zp + base + wbase);
  const v4f* x4 = (const v4f*)(Xp + base + wbase);
  const v4f* y4 = (const v4f*)(Yp + base + wbase);
  const v4f* z4 = (const v4f*)(Zp + base + wbase);
  const v4f* h4 = (const v4f*)(Hp + base + wbase);
  const int sj = qi - wbase;  // self position inside window (may be OOR)

  // ---- Seed: every thread sorts its window's first 16 candidates ----
  // (exact d2 path, unchanged — these values become sort keys directly)
  {
    u64 s16[16];
    float cd[16];
#pragma unroll
    for (int p = 0; p < 8; ++p) {
      v2f d2 = d2pair(xs2[p], ys2[p], zs2[p], qxx, qyy, qzz);
      cd[2 * p + 0] = d2.x;
      cd[2 * p + 1] = d2.y;
    }
#pragma unroll
    for (int i = 0; i < 16; ++i) {
      u64 v = ((u64)__float_as_uint(cd[i]) << 32) | (u32)(wbase + i);
      s16[i] = (i == sj) ? SENT : v;
    }
    oems_sort<16>(s16);

    // Round A: waves 1..4 publish pre-sorted lists into funnel slots.
    if (sp >= 1 && sp <= 4) {
#pragma unroll
      for (int e = 0; e < 16; ++e)
        sBuf[ql * ROWSTR + (sp - 1) * 16 + e] = s16[e];
    }
    __syncthreads();
    if (sp == 0) {
      u64 t16[16];
#pragma unroll
      for (int e = 0; e < 16; ++e) t16[e] = s16[e];
#pragma unroll
      for (int s = 0; s < 4; ++s) {
        u64 a[16];
#pragma unroll
        for (int e = 0; e < 16; ++e) a[e] = sBuf[ql * ROWSTR + s * 16 + e];
        merge16(t16, a);
      }
      // stash partial in sT while round B publishes
#pragma unroll
      for (int e = 0; e < 16; ++e) sBuf[ql * ROWSTR + TOFF + e] = t16[e];
    }
    __syncthreads();
    // Round B: waves 5..7 publish.
    if (sp >= 5) {
#pragma unroll
      for (int e = 0; e < 16; ++e)
        sBuf[ql * ROWSTR + (sp - 5) * 16 + e] = s16[e];
    }
    __syncthreads();
    if (sp == 0) {
      u64 t16[16];
#pragma unroll
      for (int e = 0; e < 16; ++e) t16[e] = sBuf[ql * ROWSTR + TOFF + e];
#pragma unroll
      for (int s = 0; s < 3; ++s) {
        u64 a[16];
#pragma unroll
        for (int e = 0; e < 16; ++e) a[e] = sBuf[ql * ROWSTR + s * 16 + e];
        merge16(t16, a);
      }
#pragma unroll
      for (int e = 0; e < 16; ++e) sBuf[ql * ROWSTR + TOFF + e] = t16[e];
      sThr[ql] = __uint_as_float((u32)(t16[15] >> 32));
    }
    __syncthreads();
  }
  float thr = sThr[ql];

  // prune threshold in s-space: d2 <= thr+eps  <=>  hc - c.q <= sthr
  const float qn = qx * qx + qy * qy + qz * qz;
  float sthr = 0.5f * (thr + PMARGIN - qn);

  // self-exclusion mask precompute (avoids per-candidate j!=qi compare)
  const int selfgrp = (sj >= 0 && sj < WIN) ? (sj >> 3) : -1;
  const u32 selfbit = 1u << (sj & 7);

  // ---- Main scan: doubling phases; digest wave rotates (1..5) ----
#pragma unroll
  for (int ph = 0; ph < 5; ++ph) {
    const int cstart = 16 << ph;  // [16,32),[32,64),...,[256,512)
    const int cend = 32 << ph;
    for (int g = cstart; g < cend; g += GRP) {
      const int gq = g >> 2;
      v4f XA = x4[gq], XB = x4[gq + 1];
      v4f YA = y4[gq], YB = y4[gq + 1];
      v4f ZA = z4[gq], ZB = z4[gq + 1];
      v4f HA = h4[gq], HB = h4[gq + 1];
      // s = hc - c.q via 3 packed FMAs per 4 candidates
      v4f sA = __builtin_elementwise_fma(
          -ZA, qz4,
          __builtin_elementwise_fma(
              -YA, qy4, __builtin_elementwise_fma(-XA, qx4, HA)));
      v4f sB = __builtin_elementwise_fma(
          -ZB, qz4,
          __builtin_elementwise_fma(
              -YB, qy4, __builtin_elementwise_fma(-XB, qx4, HB)));
      v4f m4 = __builtin_elementwise_min(sA, sB);
      float m = fminf(fminf(m4.x, m4.y), fminf(m4.z, m4.w));
      if (__any(m <= sthr)) {
        u32 want = 0;
#pragma unroll
        for (int i = 0; i < 4; ++i)
          want |= (sA[i] <= sthr) ? (1u << i) : 0u;
#pragma unroll
        for (int i = 0; i < 4; ++i)
          want |= (sB[i] <= sthr) ? (1u << (4 + i)) : 0u;
        if ((g >> 3) == selfgrp) want &= ~selfbit;
        if (__any(want)) {
#pragma unroll
          for (int i = 0; i < GRP; ++i) {
            if (want & (1u << i)) {
              float cx = (i < 4) ? XA[i & 3] : XB[i & 3];
              float cy = (i < 4) ? YA[i & 3] : YB[i & 3];
              float cz = (i < 4) ? ZA[i & 3] : ZB[i & 3];
              float d2 = d2s(cx, cy, cz, qx, qy, qz);  // exact, bit-ordered
              u32 slot = atomicAdd(&sCnt[ql], 1u);
              if (slot < BUFCAP)
                sBuf[ql * ROWSTR + slot] =
                    ((u64)__float_as_uint(d2) << 32) | (u32)(wbase + g + i);
            }
          }
        }
      }
    }
    __syncthreads();
    if (sp == ph + 1) {  // rotating digest wave (1..5)
      int n = (int)sCnt[ql];
      n = n < BUFCAP ? n : BUFCAP;
      if (__any(n > 0)) {
        u64 t16[16];
#pragma unroll
        for (int e = 0; e < 16; ++e) t16[e] = sBuf[ql * ROWSTR + TOFF + e];
        for (int k = 0; __any(k < n); k += 16) {
          u64 a[16];
#pragma unroll
          for (int e = 0; e < 16; ++e)
            a[e] = (k + e < n) ? sBuf[ql * ROWSTR + k + e] : SENT;
          oems_sort<16>(a);
          merge16(t16, a);
        }
#pragma unroll
        for (int e = 0; e < 16; ++e) sBuf[ql * ROWSTR + TOFF + e] = t16[e];
        sThr[ql] = __uint_as_float((u32)(t16[15] >> 32));
      }
      sCnt[ql] = 0;
    }
    __syncthreads();
    thr = sThr[ql];
    sthr = 0.5f * (thr + PMARGIN - qn);
  }

  // ---- Epilogue phase 1 (waves 0-3): partial M over 4 neighbors each ----
  // Thread (q = tid&63, quarter k = tid>>6) -> partials into dead funnel
  // floats [k*25, k*25+24) of row q (< float offset 100; sT starts at 128).
  if (sp < 4) {
    const int k = sp;
    u64 pv[4];
#pragma unroll
    for (int e = 0; e < 4; ++e)
      pv[e] = sBuf[ql * ROWSTR + TOFF + k * 4 + e];
    float ncx[4], ncy[4], ncz[4];
    float dd[4];
#pragma unroll
    for (int e = 0; e < 4; ++e) {
      int id = base + (int)(u32)pv[e];  // independent gathers
      ncx[e] = Xp[id];
      ncy[e] = Yp[id];
      ncz[e] = Zp[id];
      dd[e] = __uint_as_float((u32)(pv[e] >> 32));
    }
    float M[24];
#pragma unroll
    for (int j = 0; j < 24; ++j) M[j] = 0.f;
#pragma unroll
    for (int e = 0; e < 4; ++e) {
      float rx = ncx[e] - qx;  // sender - receiver
      float ry = ncy[e] - qy;
      float rz = ncz[e] - qz;
      float dist = sqrtf(dd[e]);
      float inv = 1.0f / (dist + 1e-8f);
      rx *= inv; ry *= inv; rz *= inv;
      float cut = fminf(dist * 0.1f, 1.0f);
      float g[NBASIS], s = 0.f;
#pragma unroll
      for (int v = 0; v < NBASIS; ++v) {
        float t = cut - (float)v * (1.0f / 7.0f);
        g[v] = __expf(-32.0f * t * t);  // sigma = 1/8 -> 1/(2s^2) = 32
        s += g[v];
      }
      float rs = 1.0f / s;
#pragma unroll
      for (int v = 0; v < NBASIS; ++v) {
        float rb = g[v] * rs;
        M[v * 3 + 0] = fmaf(rb, rx, M[v * 3 + 0]);
        M[v * 3 + 1] = fmaf(rb, ry, M[v * 3 + 1]);
        M[v * 3 + 2] = fmaf(rb, rz, M[v * 3 + 2]);
      }
    }
    float* fp = (float*)(sBuf + ql * ROWSTR);
#pragma unroll
    for (int c = 0; c < 24; ++c) fp[k * 25 + c] = M[c];
  }
  __syncthreads();

  // ---- Reduce partials: thread (q = ql, comps sp*3..sp*3+2) ----
  {
    const float* fp = (const float*)(sBuf + ql * ROWSTR);
#pragma unroll
    for (int j0 = 0; j0 < 3; ++j0) {
      int j = sp * 3 + j0;
      float s = fp[0 * 25 + j] + fp[1 * 25 + j] + fp[2 * 25 + j] +
                fp[3 * 25 + j];
      sM[ql * 25 + j] = s;
    }
  }
  __syncthreads();

  // ---- Epilogue phase 2 (all waves): out[q][w*3+m], lane w = ql ----
  float wreg[NBASIS];
#pragma unroll
  for (int v = 0; v < NBASIS; ++v) wreg[v] = Wmat[v * OUTM + ql];
  const float scale = 0.022097086912079608f;  // (1/sqrt(8)) / 16
#pragma unroll
  for (int i = 0; i < 8; ++i) {
    int q = sp * 8 + i;  // wave-uniform -> sM broadcasts
    const float* mq = sM + q * 25;
    float a0 = 0.f, a1 = 0.f, a2 = 0.f;
#pragma unroll
    for (int v = 0; v < NBASIS; ++v) {
      a0 = fmaf(wreg[v], mq[v * 3 + 0], a0);
      a1 = fmaf(wreg[v], mq[v * 3 + 1], a1);
      a2 = fmaf(wreg[v], mq[v * 3 + 2], a2);
    }
    size_t o = (size_t)(base + qg * QPB + q) * (OUTM * 3) + ql * 3;
    out[o + 0] = a0 * scale;
    out[o + 1] = a1 * scale;
    out[o + 2] = a2 * scale;
  }
}

// coords [B*N][3] -> x/y/z planes + half-squared-norm plane.
__global__ void prep_kernel(const float* __restrict__ coords,
                            float* __restrict__ Xp, float* __restrict__ Yp,
                            float* __restrict__ Zp, float* __restrict__ Hp) {
  int i = blockIdx.x * 256 + threadIdx.x;
  if (i < NQTOT) {
    float x = coords[3 * i + 0];
    float y = coords[3 * i + 1];
    float z = coords[3 * i + 2];
    Xp[i] = x; Yp[i] = y; Zp[i] = z;
    Hp[i] = 0.5f * (x * x + y * y + z * z);
  }
}

extern "C" void kernel_launch(void* const* d_in, const int* in_sizes, int n_in,
                              void* d_out, int out_size, void* d_ws, size_t ws_size,
                              hipStream_t stream) {
  const float* coords = (const float*)d_in[0];
  const float* Wmat = (const float*)d_in[1];
  float* out = (float*)d_out;

  char* w = (char*)d_ws;
  float* Xp = (float*)(w);               // 128 KB each
  float* Yp = (float*)(w + 131072);
  float* Zp = (float*)(w + 262144);
  float* Hp = (float*)(w + 393216);      // total 512 KB

  prep_kernel<<<dim3((NQTOT + 255) / 256), dim3(256), 0, stream>>>(coords, Xp, Yp, Zp, Hp);
  se3_kernel<<<dim3(NBATCH, NPTS / QPB), dim3(TKNN), 0, stream>>>(Xp, Yp, Zp, Hp, Wmat, out);
}